// Round 12
// baseline (909.281 us; speedup 1.0000x reference)
//
#include <hip/hip_runtime.h>
#include <math.h>
#include <stdint.h>

#define NN 30000
#define EE 480000
#define MPAD 30080   // 235 * 128
#define SCAN_B 30    // ceil(NN / 1024)

typedef __attribute__((ext_vector_type(8))) short short8;
typedef __attribute__((ext_vector_type(4))) float floatx4;

// ---------------- bf16 helpers ----------------
__device__ __forceinline__ float b2f(ushort u) {
    union { uint u; float f; } c; c.u = ((uint)u) << 16; return c.f;
}
__device__ __forceinline__ ushort f2b(float f) {
    union { float f; uint u; } c; c.f = f;
    uint u = c.u;
    uint r = (u + 0x7FFFu + ((u >> 16) & 1u)) >> 16;
    return (ushort)r;
}
// fast softplus: max(x,0) + ln2 * log2(1 + 2^(-|x|*log2e))
__device__ __forceinline__ float softplus_f(float x) {
    float a = fabsf(x) * 1.44269504f;
    float t = __builtin_amdgcn_exp2f(-a);
    float l = __builtin_amdgcn_logf(1.f + t);
    return fmaxf(x, 0.f) + 0.69314718f * l;
}

// ---- async global->LDS, 16B per lane. LDS dest = wave-uniform base + lane*16.
__device__ __forceinline__ void gld_lds16(const void* g, void* lds) {
    __builtin_amdgcn_global_load_lds(
        (__attribute__((address_space(1))) void*)(uintptr_t)(g),
        (__attribute__((address_space(3))) void*)(uint32_t)(uintptr_t)(lds),
        16, 0, 0);
}

// ---- raw barrier + fine-grained vmcnt (pipeline primitives) ----
__device__ __forceinline__ void barrier_raw() {
    __asm__ volatile("s_barrier" ::: "memory");
}
template <int N>
__device__ __forceinline__ void waitcnt_vm() {
    if constexpr (N == 0) __asm__ volatile("s_waitcnt vmcnt(0)" ::: "memory");
    else if constexpr (N == 2) __asm__ volatile("s_waitcnt vmcnt(2)" ::: "memory");
    else if constexpr (N == 3) __asm__ volatile("s_waitcnt vmcnt(3)" ::: "memory");
    else if constexpr (N == 4) __asm__ volatile("s_waitcnt vmcnt(4)" ::: "memory");
    else if constexpr (N == 8) __asm__ volatile("s_waitcnt vmcnt(8)" ::: "memory");
}

// ---------------- edge pass 1: degree + col histogram ----------------
__global__ void edge_pass1(const int* __restrict__ row, const int* __restrict__ col,
                           const float* __restrict__ ew,
                           float* __restrict__ deg, int* __restrict__ counts, int E) {
    int e = blockIdx.x * blockDim.x + threadIdx.x;
    if (e >= E) return;
    atomicAdd(&deg[row[e]], ew[e]);
    atomicAdd(&counts[col[e]], 1);
}

// ---------------- hierarchical scan: part (block reduce) -------------------
__global__ __launch_bounds__(256) void scan_part(const int* __restrict__ counts,
                                                 int* __restrict__ bsums, int N) {
    __shared__ int s[256];
    int t = threadIdx.x;
    int base = blockIdx.x * 1024 + t * 4;
    int4 v = make_int4(0, 0, 0, 0);
    if (base + 3 < N) v = *(const int4*)(counts + base);
    else {
        if (base + 0 < N) v.x = counts[base + 0];
        if (base + 1 < N) v.y = counts[base + 1];
        if (base + 2 < N) v.z = counts[base + 2];
        if (base + 3 < N) v.w = counts[base + 3];
    }
    s[t] = v.x + v.y + v.z + v.w;
    __syncthreads();
    for (int off = 1; off < 256; off <<= 1) {
        int x = (t >= off) ? s[t - off] : 0;
        __syncthreads();
        s[t] += x;
        __syncthreads();
    }
    if (t == 255) bsums[blockIdx.x] = s[255];
}

// ---------------- hierarchical scan: tops (1 wave, exclusive) --------------
__global__ void scan_tops(int* __restrict__ bsums) {
    int lane = threadIdx.x & 63;
    int orig = (lane < SCAN_B) ? bsums[lane] : 0;
    int v = orig;
    #pragma unroll
    for (int off = 1; off < 64; off <<= 1) {
        int x = __shfl_up(v, off);
        if (lane >= off) v += x;
    }
    if (lane < SCAN_B) bsums[lane] = v - orig;   // exclusive block base
}

// ---------------- hierarchical scan: final (write offs + cursor) -----------
__global__ __launch_bounds__(256) void scan_final(
        const int* __restrict__ counts, const int* __restrict__ bsums,
        int* __restrict__ offs, int* __restrict__ cursor, int N) {
    __shared__ int s[256];
    int t = threadIdx.x;
    int base = blockIdx.x * 1024 + t * 4;
    int4 v = make_int4(0, 0, 0, 0);
    if (base + 3 < N) v = *(const int4*)(counts + base);
    else {
        if (base + 0 < N) v.x = counts[base + 0];
        if (base + 1 < N) v.y = counts[base + 1];
        if (base + 2 < N) v.z = counts[base + 2];
        if (base + 3 < N) v.w = counts[base + 3];
    }
    int sum = v.x + v.y + v.z + v.w;
    s[t] = sum;
    __syncthreads();
    for (int off = 1; off < 256; off <<= 1) {
        int x = (t >= off) ? s[t - off] : 0;
        __syncthreads();
        s[t] += x;
        __syncthreads();
    }
    int tb = s[t] - sum + bsums[blockIdx.x];   // exclusive base for this thread
    int4 o;
    o.x = tb;
    o.y = o.x + v.x;
    o.z = o.y + v.y;
    o.w = o.z + v.z;
    if (base + 3 < N) {
        *(int4*)(offs + base) = o;
        *(int4*)(cursor + base) = o;
    } else {
        if (base + 0 < N) { offs[base + 0] = o.x; cursor[base + 0] = o.x; }
        if (base + 1 < N) { offs[base + 1] = o.y; cursor[base + 1] = o.y; }
        if (base + 2 < N) { offs[base + 2] = o.z; cursor[base + 2] = o.z; }
        if (base + 3 < N) { offs[base + 3] = o.w; cursor[base + 3] = o.w; }
    }
    if (blockIdx.x == 0 && t == 0) offs[N] = EE;  // total = edge count
}

// ---------------- edge pass 2: scatter into CSR-by-col ----------------
__global__ void edge_pass2(const int* __restrict__ row, const int* __restrict__ col,
                           const float* __restrict__ ew, const float* __restrict__ deg,
                           int* __restrict__ cursor,
                           int* __restrict__ csr_row, float* __restrict__ csr_w, int E) {
    int e = blockIdx.x * blockDim.x + threadIdx.x;
    if (e >= E) return;
    int r = row[e];
    float d = deg[r];
    float wv = (d > 0.f) ? (-ew[e] / d) : 0.f;  // -(2/lmax)*deg_inv*ew, lmax=2
    int pos = atomicAdd(&cursor[col[e]], 1);
    csr_row[pos] = r;
    csr_w[pos] = wv;
}

// ---------------- x (fp32) -> dense bf16 (N,128) ----------------
__global__ void copy_x_kernel(const float* __restrict__ x, ushort* __restrict__ out,
                              int total4) {
    int idx = blockIdx.x * blockDim.x + threadIdx.x;
    if (idx >= total4) return;
    float4 v = *(const float4*)(x + idx * 4);
    ushort4 o;
    o.x = f2b(v.x); o.y = f2b(v.y); o.z = f2b(v.z); o.w = f2b(v.w);
    *(ushort4*)(out + idx * 4) = o;
}

// ---------------- all weights -> bf16 transposed, one dispatch -------------
__global__ void wconv_all(const float* __restrict__ W1, const float* __restrict__ W2,
                          const float* __restrict__ W3, const float* __restrict__ W4,
                          const float* __restrict__ W5, const float* __restrict__ W6,
                          ushort* __restrict__ B1, ushort* __restrict__ B2,
                          ushort* __restrict__ B3, ushort* __restrict__ B4,
                          ushort* __restrict__ B5, ushort* __restrict__ B6) {
    int idx = blockIdx.x * blockDim.x + threadIdx.x;
    if (idx < 6144) {                       // L1: 48*128
        int row = idx >> 7, k = idx & 127;
        int j = row >> 4, n = row & 15;
        B1[idx] = f2b(W1[(j * 128 + k) * 16 + n]);
    } else if (idx < 8192) {                // L2: 32*64, K=48
        int t = idx - 6144; int n = t >> 6, k = t & 63;
        B2[t] = f2b(k < 48 ? W2[k * 32 + n] : 0.f);
    } else if (idx < 14336) {               // L3: 64*96
        int t = idx - 8192; int n = t / 96, k = t - n * 96;
        B3[t] = f2b(W3[k * 64 + n]);
    } else if (idx < 38912) {               // L4: 128*192
        int t = idx - 14336; int n = t / 192, k = t - n * 192;
        B4[t] = f2b(W4[k * 128 + n]);
    } else if (idx < 137216) {              // L5: 256*384
        int t = idx - 38912; int n = t / 384, k = t - n * 384;
        B5[t] = f2b(W5[k * 256 + n]);
    } else if (idx < 530432) {              // L6: 512*768
        int t = idx - 137216; int n = t / 768, k = t - n * 768;
        B6[t] = f2b(W6[k * 512 + n]);
    }
}

// ---------------- SpMV gather, small FI (16/32): node-packed waves ---------
template <int FI>
__global__ __launch_bounds__(256) void lmv_bf16(
        const ushort* __restrict__ A, ushort* __restrict__ Out,
        const ushort* __restrict__ Sub, int ldi, int ldo,
        const int* __restrict__ offs, const int* __restrict__ rows,
        const float* __restrict__ w, float scale, int N) {
    constexpr int NPW = 64 / FI;
    int wave = threadIdx.x >> 6;
    int lane = threadIdx.x & 63;
    int sub = lane / FI;
    int fbase = lane & (FI - 1);
    int node = blockIdx.x * (4 * NPW) + wave * NPW + sub;
    if (node >= N) return;
    int e0 = offs[node], e1 = offs[node + 1];
    float acc[4];
    #pragma unroll
    for (int c = 0; c < 4; ++c) acc[c] = 0.f;
    int e = e0;
    for (; e + 4 <= e1; e += 4) {
        int r0 = rows[e], r1 = rows[e + 1], r2 = rows[e + 2], r3 = rows[e + 3];
        float w0 = w[e], w1 = w[e + 1], w2 = w[e + 2], w3 = w[e + 3];
        acc[0] += w0 * b2f(A[(size_t)r0 * ldi + fbase]);
        acc[1] += w1 * b2f(A[(size_t)r1 * ldi + fbase]);
        acc[2] += w2 * b2f(A[(size_t)r2 * ldi + fbase]);
        acc[3] += w3 * b2f(A[(size_t)r3 * ldi + fbase]);
    }
    for (; e < e1; ++e)
        acc[0] += w[e] * b2f(A[(size_t)rows[e] * ldi + fbase]);
    float a = (acc[0] + acc[1]) + (acc[2] + acc[3]);
    ushort* o = Out + (size_t)node * ldo + fbase;
    if (Sub) {
        const ushort* s = Sub + (size_t)node * ldo + fbase;
        *o = f2b(scale * a - b2f(*s));
    } else {
        *o = f2b(scale * a);
    }
}

// ---- L1 tail fused: z3 = Lhat@Z2 (16-wide), h1 = softplus(Y0+Z1+2z3-Y2+b) --
__global__ __launch_bounds__(256) void lmv_l1_final(
        const ushort* __restrict__ Z,    // (N,32) = [Z1|Z2]
        const ushort* __restrict__ Y,    // (N,48) = [Y0|Y1|Y2]
        const float* __restrict__ b,     // b1[16]
        ushort* __restrict__ Out,        // (N,64), cols [0,16)
        const int* __restrict__ offs, const int* __restrict__ rows,
        const float* __restrict__ w, int N) {
    int wave = threadIdx.x >> 6;
    int lane = threadIdx.x & 63;
    int sub = lane >> 4, f = lane & 15;
    int node = blockIdx.x * 16 + wave * 4 + sub;
    if (node >= N) return;
    int e0 = offs[node], e1 = offs[node + 1];
    const ushort* Z2 = Z + 16;
    float acc[4];
    #pragma unroll
    for (int c = 0; c < 4; ++c) acc[c] = 0.f;
    int e = e0;
    for (; e + 4 <= e1; e += 4) {
        int r0 = rows[e], r1 = rows[e + 1], r2 = rows[e + 2], r3 = rows[e + 3];
        float w0 = w[e], w1 = w[e + 1], w2 = w[e + 2], w3 = w[e + 3];
        acc[0] += w0 * b2f(Z2[(size_t)r0 * 32 + f]);
        acc[1] += w1 * b2f(Z2[(size_t)r1 * 32 + f]);
        acc[2] += w2 * b2f(Z2[(size_t)r2 * 32 + f]);
        acc[3] += w3 * b2f(Z2[(size_t)r3 * 32 + f]);
    }
    for (; e < e1; ++e)
        acc[0] += w[e] * b2f(Z2[(size_t)rows[e] * 32 + f]);
    float z3 = (acc[0] + acc[1]) + (acc[2] + acc[3]);
    float y0 = b2f(Y[(size_t)node * 48 + f]);
    float y2 = b2f(Y[(size_t)node * 48 + 32 + f]);
    float z1 = b2f(Z[(size_t)node * 32 + f]);
    float v = y0 + z1 + 2.f * z3 - y2 + b[f];
    Out[(size_t)node * 64 + f] = f2b(softplus_f(v));
}

// ---------------- SpMV gather, vectorized (FI = VEC*64), scalar CSR --------
// One wave per node; lane reads VEC contiguous bf16 -> one VMEM per edge.
// CSR via readfirstlane -> SGPR loop; 16 independent accumulator chains
// (covers the ~16 avg edges in one latency round).
template <int VEC>
__global__ __launch_bounds__(256) void lmv_vec(
        const ushort* __restrict__ A, ushort* __restrict__ Out,
        const ushort* __restrict__ Sub, int ld,
        const int* __restrict__ offs, const int* __restrict__ rows,
        const float* __restrict__ w, float scale) {
    constexpr int CH = 16;
    int node = blockIdx.x * 4 + (threadIdx.x >> 6);   // NN % 4 == 0, no guard
    int lane = threadIdx.x & 63;
    int fbase = lane * VEC;
    int e0 = __builtin_amdgcn_readfirstlane(offs[node]);
    int e1 = __builtin_amdgcn_readfirstlane(offs[node + 1]);
    float acc[CH][VEC];
    #pragma unroll
    for (int c = 0; c < CH; ++c)
        #pragma unroll
        for (int v = 0; v < VEC; ++v) acc[c][v] = 0.f;
    int e = e0;
    for (; e + CH <= e1; e += CH) {
        #pragma unroll
        for (int c = 0; c < CH; ++c) {
            int r = rows[e + c];            // scalar (uniform) load
            float we = w[e + c];
            const ushort* pr = A + (size_t)r * ld + fbase;
            if constexpr (VEC == 4) {
                ushort4 u = *(const ushort4*)pr;
                acc[c][0] += we * b2f(u.x); acc[c][1] += we * b2f(u.y);
                acc[c][2] += we * b2f(u.z); acc[c][3] += we * b2f(u.w);
            } else if constexpr (VEC == 2) {
                ushort2 u = *(const ushort2*)pr;
                acc[c][0] += we * b2f(u.x); acc[c][1] += we * b2f(u.y);
            } else {
                acc[c][0] += we * b2f(*pr);
            }
        }
    }
    for (; e < e1; ++e) {
        int c = e & (CH - 1);
        int r = rows[e];
        float we = w[e];
        const ushort* pr = A + (size_t)r * ld + fbase;
        if constexpr (VEC == 4) {
            ushort4 u = *(const ushort4*)pr;
            acc[c][0] += we * b2f(u.x); acc[c][1] += we * b2f(u.y);
            acc[c][2] += we * b2f(u.z); acc[c][3] += we * b2f(u.w);
        } else if constexpr (VEC == 2) {
            ushort2 u = *(const ushort2*)pr;
            acc[c][0] += we * b2f(u.x); acc[c][1] += we * b2f(u.y);
        } else {
            acc[c][0] += we * b2f(*pr);
        }
    }
    #pragma unroll
    for (int c = 1; c < CH; ++c)
        #pragma unroll
        for (int v = 0; v < VEC; ++v) acc[0][v] += acc[c][v];
    ushort* o = Out + (size_t)node * ld + fbase;
    if (Sub) {
        const ushort* s = Sub + (size_t)node * ld + fbase;
        ushort tmp[VEC];
        #pragma unroll
        for (int v = 0; v < VEC; ++v) tmp[v] = f2b(scale * acc[0][v] - b2f(s[v]));
        #pragma unroll
        for (int v = 0; v < VEC; ++v) o[v] = tmp[v];
    } else {
        #pragma unroll
        for (int v = 0; v < VEC; ++v) o[v] = f2b(scale * acc[0][v]);
    }
}

// ---------------- MFMA GEMM, BN<=64 path, BK=32, double-buffered LDS -------
// Pipeline: raw s_barrier + fine s_waitcnt vmcnt(N) keeps next tile's
// global_load_lds in flight across the barrier. N = this wave's loads/stage
// (conservative min across waves when non-uniform). FC race fixed in R10;
// the pipeline itself was audited sound.
template <int BN, bool ACT = true>
__global__ __launch_bounds__(256) void gemm_mfma(
        const ushort* __restrict__ A, int lda, int K,
        const ushort* __restrict__ Bt,
        const float* __restrict__ bias,
        ushort* __restrict__ Out, int ldo) {
    constexpr int BM = 128, BK = 32;
    constexpr int SM = 32;                    // 4 waves along M
    constexpr int FM = 2;
    constexpr int FN = BN / 16;
    constexpr int CB = BN / 16;               // B staging calls (1KB each)
    constexpr int WAITN = (BN == 64) ? 3 : 2; // per-wave loads/stage (min)
    __shared__ __align__(16) ushort As[2][BM][BK];
    __shared__ __align__(16) ushort Bs[2][BN][BK];
    int tid = threadIdx.x;
    int wv = tid >> 6, ln = tid & 63;
    int q = ln >> 4, r16 = ln & 15;
    int m0 = blockIdx.x * BM;

    int lrow = ln >> 2;
    int gseg = (ln & 3) ^ ((ln >> 3) & 3);
    const ushort* Abase = A + (size_t)(m0 + lrow) * lda + gseg * 8;
    const ushort* Bbase = Bt + (size_t)lrow * K + gseg * 8;

    floatx4 acc[FM][FN];
    #pragma unroll
    for (int i = 0; i < FM; ++i)
        #pragma unroll
        for (int j = 0; j < FN; ++j) acc[i][j] = (floatx4){0.f, 0.f, 0.f, 0.f};

    int sw = (q ^ ((r16 >> 1) & 3)) * 8;
    int aoff[FM], boff[FN];
    #pragma unroll
    for (int i = 0; i < FM; ++i) aoff[i] = (wv * SM + i * 16 + r16) * BK + sw;
    #pragma unroll
    for (int j = 0; j < FN; ++j) boff[j] = (j * 16 + r16) * BK + sw;

    auto stage = [&](int b, int k0) {
        gld_lds16(Abase + (size_t)(wv * 16) * lda + k0, &As[b][wv * 16][0]);
        gld_lds16(Abase + (size_t)(64 + wv * 16) * lda + k0, &As[b][64 + wv * 16][0]);
        if constexpr (CB == 4) {
            gld_lds16(Bbase + (size_t)(wv * 16) * K + k0, &Bs[b][wv * 16][0]);
        } else {
            if (wv < CB) gld_lds16(Bbase + (size_t)(wv * 16) * K + k0, &Bs[b][wv * 16][0]);
        }
    };
    auto compute = [&](int b) {
        const ushort* ldsA = &As[b][0][0];
        const ushort* ldsB = &Bs[b][0][0];
        short8 af[FM], bf[FN];
        #pragma unroll
        for (int i = 0; i < FM; ++i) af[i] = *(const short8*)(ldsA + aoff[i]);
        #pragma unroll
        for (int j = 0; j < FN; ++j) bf[j] = *(const short8*)(ldsB + boff[j]);
        #pragma unroll
        for (int i = 0; i < FM; ++i)
            #pragma unroll
            for (int j = 0; j < FN; ++j)
                acc[i][j] = __builtin_amdgcn_mfma_f32_16x16x32_bf16(
                    af[i], bf[j], acc[i][j], 0, 0, 0);
    };

    int nIter = K / BK;
    stage(0, 0);
    for (int i = 0; i < nIter; ++i) {
        int cur = i & 1;
        barrier_raw();                    // all waves done reading buf cur^1
        if (i + 1 < nIter) {
            stage(cur ^ 1, (i + 1) * BK); // prefetch next tile
            waitcnt_vm<WAITN>();          // own tile-i loads landed
        } else {
            waitcnt_vm<0>();
        }
        barrier_raw();                    // tile i complete in LDS
        compute(cur);
    }
    #pragma unroll
    for (int i = 0; i < FM; ++i) {
        #pragma unroll
        for (int j = 0; j < FN; ++j) {
            int n = j * 16 + r16;
            float bv = ACT ? bias[n] : 0.f;
            #pragma unroll
            for (int r = 0; r < 4; ++r) {
                int m = m0 + wv * SM + i * 16 + q * 4 + r;
                float v = acc[i][j][r] + bv;
                Out[(size_t)m * ldo + n] = f2b(ACT ? softplus_f(v) : v);
            }
        }
    }
}

// ---------------- MFMA GEMM, BN=128 path, BK=64 + double-buffered LDS ------
// 8 gld_lds16 per wave per stage; vmcnt(8) keeps next tile in flight across
// the barrier. FC: fused h@fcw -> per-(yb,wn) partial slot (8 total; wn waves
// see different column halves and must not share a destination).
template <bool FC = false, int YB = 0>
__global__ __launch_bounds__(256) void gemm_bk64(
        const ushort* __restrict__ A, int lda, int K,
        const ushort* __restrict__ Bt,
        const float* __restrict__ bias,
        ushort* __restrict__ Out, int ldo,
        const float* __restrict__ fcw, float* __restrict__ fcout) {
    constexpr int BM = 128, BN = 128, BK = 64;
    __shared__ __align__(16) ushort As[2][BM][BK];   // 2 x 16 KB
    __shared__ __align__(16) ushort Bs[2][BN][BK];   // 2 x 16 KB
    int tid = threadIdx.x;
    int wv = tid >> 6, ln = tid & 63;
    int wm = wv & 1, wn = wv >> 1;
    int q = ln >> 4, r16 = ln & 15;
    int yb = blockIdx.x & ((1 << YB) - 1);
    int xb = blockIdx.x >> YB;
    int m0 = xb * BM;
    int n0 = yb * BN;

    int lrow8 = ln >> 3, slds = ln & 7;
    int gseg = slds ^ lrow8;
    const ushort* Abase = A + (size_t)(m0 + lrow8) * lda + gseg * 8;
    const ushort* Bbase = Bt + (size_t)(n0 + lrow8) * K + gseg * 8;

    floatx4 acc[4][4];
    #pragma unroll
    for (int i = 0; i < 4; ++i)
        #pragma unroll
        for (int j = 0; j < 4; ++j) acc[i][j] = (floatx4){0.f, 0.f, 0.f, 0.f};

    int r7 = r16 & 7;
    int aoff[2][4], boff[2][4];
    #pragma unroll
    for (int s = 0; s < 2; ++s) {
        int segp = ((s * 4 + q) ^ r7) * 8;
        #pragma unroll
        for (int i = 0; i < 4; ++i) {
            aoff[s][i] = (wm * 64 + i * 16 + r16) * BK + segp;
            boff[s][i] = (wn * 64 + i * 16 + r16) * BK + segp;
        }
    }

    auto stage = [&](int b, int k0) {
        #pragma unroll
        for (int g = 0; g < 4; ++g)
            gld_lds16(Abase + (size_t)(wv * 8 + g * 32) * lda + k0,
                      &As[b][wv * 8 + g * 32][0]);
        #pragma unroll
        for (int g = 0; g < 4; ++g)
            gld_lds16(Bbase + (size_t)(wv * 8 + g * 32) * K + k0,
                      &Bs[b][wv * 8 + g * 32][0]);
    };
    auto compute = [&](int b) {
        const ushort* ldsA = &As[b][0][0];
        const ushort* ldsB = &Bs[b][0][0];
        #pragma unroll
        for (int s = 0; s < 2; ++s) {
            short8 af[4], bf[4];
            #pragma unroll
            for (int i = 0; i < 4; ++i) af[i] = *(const short8*)(ldsA + aoff[s][i]);
            #pragma unroll
            for (int j = 0; j < 4; ++j) bf[j] = *(const short8*)(ldsB + boff[s][j]);
            #pragma unroll
            for (int i = 0; i < 4; ++i)
                #pragma unroll
                for (int j = 0; j < 4; ++j)
                    acc[i][j] = __builtin_amdgcn_mfma_f32_16x16x32_bf16(
                        af[i], bf[j], acc[i][j], 0, 0, 0);
        }
    };

    int nIter = K / BK;
    stage(0, 0);
    for (int i = 0; i < nIter; ++i) {
        int cur = i & 1;
        barrier_raw();                    // all waves done reading buf cur^1
        if (i + 1 < nIter) {
            stage(cur ^ 1, (i + 1) * BK);
            waitcnt_vm<8>();              // own tile-i loads landed
        } else {
            waitcnt_vm<0>();
        }
        barrier_raw();                    // tile i complete in LDS
        compute(cur);
    }

    if constexpr (FC) {
        int pb = yb * 2 + wn;   // per-(yb,wn) partial slot — no shared dst
        #pragma unroll
        for (int i = 0; i < 4; ++i) {
            #pragma unroll
            for (int r = 0; r < 4; ++r) {
                float p0 = 0.f, p1 = 0.f, p2 = 0.f;
                #pragma unroll
                for (int j = 0; j < 4; ++j) {
                    int n = n0 + wn * 64 + j * 16 + r16;
                    float v = softplus_f(acc[i][j][r] + bias[n]);
                    p0 += v * fcw[n * 3 + 0];
                    p1 += v * fcw[n * 3 + 1];
                    p2 += v * fcw[n * 3 + 2];
                }
                #pragma unroll
                for (int off = 1; off < 16; off <<= 1) {
                    p0 += __shfl_xor(p0, off);
                    p1 += __shfl_xor(p1, off);
                    p2 += __shfl_xor(p2, off);
                }
                if (r16 == 0) {
                    int m = m0 + wm * 64 + i * 16 + q * 4 + r;
                    float* dst = fcout + ((size_t)pb * MPAD + m) * 3;
                    dst[0] = p0; dst[1] = p1; dst[2] = p2;
                }
            }
        }
    } else {
        #pragma unroll
        for (int i = 0; i < 4; ++i) {
            #pragma unroll
            for (int j = 0; j < 4; ++j) {
                int n = n0 + wn * 64 + j * 16 + r16;
                float bv = bias[n];
                #pragma unroll
                for (int r = 0; r < 4; ++r) {
                    int m = m0 + wm * 64 + i * 16 + q * 4 + r;
                    Out[(size_t)m * ldo + n] = f2b(softplus_f(acc[i][j][r] + bv));
                }
            }
        }
    }
}

// ---------------- FC partial reduce: out = sum of 8 partials + fcb ---------
__global__ __launch_bounds__(256) void fc_reduce(
        const float* __restrict__ part, const float* __restrict__ fcb,
        float* __restrict__ out) {
    int idx = blockIdx.x * blockDim.x + threadIdx.x;
    if (idx >= NN * 3) return;
    int c = idx - (idx / 3) * 3;
    float s = 0.f;
    #pragma unroll
    for (int pb = 0; pb < 8; ++pb)
        s += part[(size_t)pb * MPAD * 3 + idx];
    out[idx] = s + fcb[c];
}

static inline size_t align256(size_t x) { return (x + 255) & ~(size_t)255; }

extern "C" void kernel_launch(void* const* d_in, const int* in_sizes, int n_in,
                              void* d_out, int out_size, void* d_ws, size_t ws_size,
                              hipStream_t stream) {
    const float* x   = (const float*)d_in[0];
    const int*   ei  = (const int*)d_in[1];
    const float* ew  = (const float*)d_in[2];
    const float* W[6]  = { (const float*)d_in[4],  (const float*)d_in[6],
                           (const float*)d_in[8],  (const float*)d_in[10],
                           (const float*)d_in[12], (const float*)d_in[14] };
    const float* Bv[6] = { (const float*)d_in[5],  (const float*)d_in[7],
                           (const float*)d_in[9],  (const float*)d_in[11],
                           (const float*)d_in[13], (const float*)d_in[15] };
    const float* fc_w = (const float*)d_in[16];
    const float* fc_b = (const float*)d_in[17];
    float* out = (float*)d_out;

    const int* e_row = ei;        // edge_index[0]
    const int* e_col = ei + EE;   // edge_index[1]

    // layers 2..6 (index 1..5)
    const int fi_arr[5]   = { 16, 32, 64, 128, 256 };
    const int fo_arr[5]   = { 32, 64, 128, 256, 512 };
    const int Kpad_arr[5] = { 64, 96, 192, 384, 768 };
    const int ldo_arr[5]  = { 96, 192, 384, 768, 512 };

    // ---- workspace carve ----
    char* p = (char*)d_ws;
    float* deg    = (float*)p; p += align256((size_t)NN * 4);
    int*   counts = (int*)p;   p += align256((size_t)NN * 4);
    int*   offs   = (int*)p;   p += align256((size_t)(NN + 1) * 4);
    int*   cursor = (int*)p;   p += align256((size_t)NN * 4);
    int*   bsums  = (int*)p;   p += align256((size_t)SCAN_B * 4);
    int*   csr_r  = (int*)p;   p += align256((size_t)EE * 4);
    float* csr_w  = (float*)p; p += align256((size_t)EE * 4);
    ushort* Bt1   = (ushort*)p; p += align256((size_t)48 * 128 * 2);
    ushort* Bt[5];
    for (int L = 0; L < 5; ++L) {
        Bt[L] = (ushort*)p;
        p += align256((size_t)fo_arr[L] * Kpad_arr[L] * 2);
    }
    float* fcpart = (float*)p; p += align256((size_t)8 * MPAD * 3 * 4);
    ushort* xb   = (ushort*)p; p += align256((size_t)MPAD * 128 * 2);
    ushort* Ybuf = (ushort*)p; p += align256((size_t)MPAD * 48 * 2);
    ushort* Zbuf = (ushort*)p; p += align256((size_t)MPAD * 32 * 2);
    ushort* buf0 = (ushort*)p; p += align256((size_t)MPAD * 768 * 2);
    ushort* buf1 = (ushort*)p; p += align256((size_t)MPAD * 768 * 2);
    (void)ws_size; (void)n_in; (void)in_sizes; (void)out_size;

    // ---- zero init: deg+counts only (adjacent -> one memset). Activation
    // buffer poison is harmless (pad rows never feed real rows; K-pad cols
    // multiply zeroed Bt cols). fcpart fully written before fc_reduce.
    hipMemsetAsync(deg, 0, align256((size_t)NN * 4) + (size_t)NN * 4, stream);

    // ---- graph preprocessing ----
    {
        int blocks = (EE + 255) / 256;
        edge_pass1<<<blocks, 256, 0, stream>>>(e_row, e_col, ew, deg, counts, EE);
        scan_part<<<SCAN_B, 256, 0, stream>>>(counts, bsums, NN);
        scan_tops<<<1, 64, 0, stream>>>(bsums);
        scan_final<<<SCAN_B, 256, 0, stream>>>(counts, bsums, offs, cursor, NN);
        edge_pass2<<<blocks, 256, 0, stream>>>(e_row, e_col, ew, deg, cursor, csr_r, csr_w, EE);
    }

    // ---- all weights -> bf16 transposed, one dispatch ----
    wconv_all<<<(530432 + 255) / 256, 256, 0, stream>>>(
        W[0], W[1], W[2], W[3], W[4], W[5],
        Bt1, Bt[0], Bt[1], Bt[2], Bt[3], Bt[4]);

    // ---- x -> bf16 dense (N,128) ----
    copy_x_kernel<<<(NN * 128 / 4 + 255) / 256, 256, 0, stream>>>(x, xb, NN * 128 / 4);

    // ---- Layer 1 in output space: Y = x @ [W0|W1|W2]  (30080 x 48, K=128) --
    gemm_mfma<48, false><<<dim3(MPAD / 128), 256, 0, stream>>>(
        xb, 128, 128, Bt1, nullptr, Ybuf, 48);
    // Z = Lhat @ [Y1|Y2]  (32-wide)
    lmv_bf16<32><<<(NN + 7) / 8, 256, 0, stream>>>(
        Ybuf + 16, Zbuf, nullptr, 48, 32, offs, csr_r, csr_w, 1.0f, NN);
    // fused: z3 = Lhat@Z2 ; h1 = softplus(Y0+Z1+2z3-Y2+b1) -> buf1 [0,16), ld 64
    lmv_l1_final<<<(NN + 15) / 16, 256, 0, stream>>>(
        Zbuf, Ybuf, Bv[0], buf1, offs, csr_r, csr_w, NN);

    // ---- Layers 2..6 ----
    ushort* Abuf[5] = { buf1, buf0, buf1, buf0, buf1 };
    ushort* Obuf[5] = { buf0, buf1, buf0, buf1, buf0 };

    for (int L = 0; L < 5; ++L) {
        int fi = fi_arr[L];
        int ldA = Kpad_arr[L];
        int ldO = ldo_arr[L];
        ushort* A = Abuf[L];
        ushort* O = Obuf[L];

        // two SpMV passes: Tx1 = Lhat@Tx0; Tx2 = 2*Lhat@Tx1 - Tx0
        switch (fi) {
            case 16:
                lmv_bf16<16><<<(NN + 15) / 16, 256, 0, stream>>>(
                    A, A + fi, nullptr, ldA, ldA, offs, csr_r, csr_w, 1.0f, NN);
                lmv_bf16<16><<<(NN + 15) / 16, 256, 0, stream>>>(
                    A + fi, A + 2 * fi, A, ldA, ldA, offs, csr_r, csr_w, 2.0f, NN);
                break;
            case 32:
                lmv_bf16<32><<<(NN + 7) / 8, 256, 0, stream>>>(
                    A, A + fi, nullptr, ldA, ldA, offs, csr_r, csr_w, 1.0f, NN);
                lmv_bf16<32><<<(NN + 7) / 8, 256, 0, stream>>>(
                    A + fi, A + 2 * fi, A, ldA, ldA, offs, csr_r, csr_w, 2.0f, NN);
                break;
            case 64:
                lmv_vec<1><<<NN / 4, 256, 0, stream>>>(
                    A, A + fi, nullptr, ldA, offs, csr_r, csr_w, 1.0f);
                lmv_vec<1><<<NN / 4, 256, 0, stream>>>(
                    A + fi, A + 2 * fi, A, ldA, offs, csr_r, csr_w, 2.0f);
                break;
            case 128:
                lmv_vec<2><<<NN / 4, 256, 0, stream>>>(
                    A, A + fi, nullptr, ldA, offs, csr_r, csr_w, 1.0f);
                lmv_vec<2><<<NN / 4, 256, 0, stream>>>(
                    A + fi, A + 2 * fi, A, ldA, offs, csr_r, csr_w, 2.0f);
                break;
            default:  // 256
                lmv_vec<4><<<NN / 4, 256, 0, stream>>>(
                    A, A + fi, nullptr, ldA, offs, csr_r, csr_w, 1.0f);
                lmv_vec<4><<<NN / 4, 256, 0, stream>>>(
                    A + fi, A + 2 * fi, A, ldA, offs, csr_r, csr_w, 2.0f);
                break;
        }

        int K = Kpad_arr[L];
        switch (fo_arr[L]) {
            case 32:
                gemm_mfma<32><<<dim3(MPAD / 128), 256, 0, stream>>>(
                    A, ldA, K, Bt[L], Bv[L + 1], O, ldO);
                break;
            case 64:
                gemm_mfma<64><<<dim3(MPAD / 128), 256, 0, stream>>>(
                    A, ldA, K, Bt[L], Bv[L + 1], O, ldO);
                break;
            case 128:   // K=192, BK=64 DB
                gemm_bk64<false, 0><<<dim3(MPAD / 128), 256, 0, stream>>>(
                    A, ldA, K, Bt[L], Bv[L + 1], O, ldO, nullptr, nullptr);
                break;
            case 256:   // K=384, y-inner (id&1)
                gemm_bk64<false, 1><<<dim3(MPAD / 128 * 2), 256, 0, stream>>>(
                    A, ldA, K, Bt[L], Bv[L + 1], O, ldO, nullptr, nullptr);
                break;
            default:    // 512 = layer 6: K=768, fused FC -> 8 partial buffers
                gemm_bk64<true, 2><<<dim3(MPAD / 128 * 4), 256, 0, stream>>>(
                    A, ldA, K, Bt[L], Bv[L + 1], nullptr, 0, fc_w, fcpart);
                break;
        }
    }

    // ---- final: out = sum of 8 FC partials + fc_b ----
    fc_reduce<<<(NN * 3 + 255) / 256, 256, 0, stream>>>(fcpart, fc_b, out);
}

// Round 13
// 485.871 us; speedup vs baseline: 1.8714x; 1.8714x over previous
//
#include <hip/hip_runtime.h>
#include <math.h>
#include <stdint.h>

#define NN 30000
#define EE 480000
#define MPAD 30080   // 235 * 128
#define SCAN_B 30    // ceil(NN / 1024)

typedef __attribute__((ext_vector_type(8))) short short8;
typedef __attribute__((ext_vector_type(4))) float floatx4;

// ---------------- bf16 helpers ----------------
__device__ __forceinline__ float b2f(ushort u) {
    union { uint u; float f; } c; c.u = ((uint)u) << 16; return c.f;
}
__device__ __forceinline__ ushort f2b(float f) {
    union { float f; uint u; } c; c.f = f;
    uint u = c.u;
    uint r = (u + 0x7FFFu + ((u >> 16) & 1u)) >> 16;
    return (ushort)r;
}
// fast softplus: max(x,0) + ln2 * log2(1 + 2^(-|x|*log2e))
__device__ __forceinline__ float softplus_f(float x) {
    float a = fabsf(x) * 1.44269504f;
    float t = __builtin_amdgcn_exp2f(-a);
    float l = __builtin_amdgcn_logf(1.f + t);
    return fmaxf(x, 0.f) + 0.69314718f * l;
}

// ---- async global->LDS, 16B per lane. LDS dest = wave-uniform base + lane*16.
__device__ __forceinline__ void gld_lds16(const void* g, void* lds) {
    __builtin_amdgcn_global_load_lds(
        (__attribute__((address_space(1))) void*)(uintptr_t)(g),
        (__attribute__((address_space(3))) void*)(uint32_t)(uintptr_t)(lds),
        16, 0, 0);
}

// ---- raw barrier + fine-grained vmcnt (pipeline primitives) ----
__device__ __forceinline__ void barrier_raw() {
    __asm__ volatile("s_barrier" ::: "memory");
}
template <int N>
__device__ __forceinline__ void waitcnt_vm() {
    if constexpr (N == 0) __asm__ volatile("s_waitcnt vmcnt(0)" ::: "memory");
    else if constexpr (N == 2) __asm__ volatile("s_waitcnt vmcnt(2)" ::: "memory");
    else if constexpr (N == 3) __asm__ volatile("s_waitcnt vmcnt(3)" ::: "memory");
    else if constexpr (N == 4) __asm__ volatile("s_waitcnt vmcnt(4)" ::: "memory");
    else if constexpr (N == 8) __asm__ volatile("s_waitcnt vmcnt(8)" ::: "memory");
}

// ---------------- edge pass 1: degree + col histogram ----------------
__global__ void edge_pass1(const int* __restrict__ row, const int* __restrict__ col,
                           const float* __restrict__ ew,
                           float* __restrict__ deg, int* __restrict__ counts, int E) {
    int e = blockIdx.x * blockDim.x + threadIdx.x;
    if (e >= E) return;
    atomicAdd(&deg[row[e]], ew[e]);
    atomicAdd(&counts[col[e]], 1);
}

// ---------------- hierarchical scan: part (block reduce) -------------------
__global__ __launch_bounds__(256) void scan_part(const int* __restrict__ counts,
                                                 int* __restrict__ bsums, int N) {
    __shared__ int s[256];
    int t = threadIdx.x;
    int base = blockIdx.x * 1024 + t * 4;
    int4 v = make_int4(0, 0, 0, 0);
    if (base + 3 < N) v = *(const int4*)(counts + base);
    else {
        if (base + 0 < N) v.x = counts[base + 0];
        if (base + 1 < N) v.y = counts[base + 1];
        if (base + 2 < N) v.z = counts[base + 2];
        if (base + 3 < N) v.w = counts[base + 3];
    }
    s[t] = v.x + v.y + v.z + v.w;
    __syncthreads();
    for (int off = 1; off < 256; off <<= 1) {
        int x = (t >= off) ? s[t - off] : 0;
        __syncthreads();
        s[t] += x;
        __syncthreads();
    }
    if (t == 255) bsums[blockIdx.x] = s[255];
}

// ---------------- hierarchical scan: tops (1 wave, exclusive) --------------
__global__ void scan_tops(int* __restrict__ bsums) {
    int lane = threadIdx.x & 63;
    int orig = (lane < SCAN_B) ? bsums[lane] : 0;
    int v = orig;
    #pragma unroll
    for (int off = 1; off < 64; off <<= 1) {
        int x = __shfl_up(v, off);
        if (lane >= off) v += x;
    }
    if (lane < SCAN_B) bsums[lane] = v - orig;   // exclusive block base
}

// ---------------- hierarchical scan: final (write offs + cursor) -----------
__global__ __launch_bounds__(256) void scan_final(
        const int* __restrict__ counts, const int* __restrict__ bsums,
        int* __restrict__ offs, int* __restrict__ cursor, int N) {
    __shared__ int s[256];
    int t = threadIdx.x;
    int base = blockIdx.x * 1024 + t * 4;
    int4 v = make_int4(0, 0, 0, 0);
    if (base + 3 < N) v = *(const int4*)(counts + base);
    else {
        if (base + 0 < N) v.x = counts[base + 0];
        if (base + 1 < N) v.y = counts[base + 1];
        if (base + 2 < N) v.z = counts[base + 2];
        if (base + 3 < N) v.w = counts[base + 3];
    }
    int sum = v.x + v.y + v.z + v.w;
    s[t] = sum;
    __syncthreads();
    for (int off = 1; off < 256; off <<= 1) {
        int x = (t >= off) ? s[t - off] : 0;
        __syncthreads();
        s[t] += x;
        __syncthreads();
    }
    int tb = s[t] - sum + bsums[blockIdx.x];   // exclusive base for this thread
    int4 o;
    o.x = tb;
    o.y = o.x + v.x;
    o.z = o.y + v.y;
    o.w = o.z + v.z;
    if (base + 3 < N) {
        *(int4*)(offs + base) = o;
        *(int4*)(cursor + base) = o;
    } else {
        if (base + 0 < N) { offs[base + 0] = o.x; cursor[base + 0] = o.x; }
        if (base + 1 < N) { offs[base + 1] = o.y; cursor[base + 1] = o.y; }
        if (base + 2 < N) { offs[base + 2] = o.z; cursor[base + 2] = o.z; }
        if (base + 3 < N) { offs[base + 3] = o.w; cursor[base + 3] = o.w; }
    }
    if (blockIdx.x == 0 && t == 0) offs[N] = EE;  // total = edge count
}

// ---------------- edge pass 2: scatter into CSR-by-col ----------------
__global__ void edge_pass2(const int* __restrict__ row, const int* __restrict__ col,
                           const float* __restrict__ ew, const float* __restrict__ deg,
                           int* __restrict__ cursor,
                           int* __restrict__ csr_row, float* __restrict__ csr_w, int E) {
    int e = blockIdx.x * blockDim.x + threadIdx.x;
    if (e >= E) return;
    int r = row[e];
    float d = deg[r];
    float wv = (d > 0.f) ? (-ew[e] / d) : 0.f;  // -(2/lmax)*deg_inv*ew, lmax=2
    int pos = atomicAdd(&cursor[col[e]], 1);
    csr_row[pos] = r;
    csr_w[pos] = wv;
}

// ---------------- x (fp32) -> dense bf16 (N,128) ----------------
__global__ void copy_x_kernel(const float* __restrict__ x, ushort* __restrict__ out,
                              int total4) {
    int idx = blockIdx.x * blockDim.x + threadIdx.x;
    if (idx >= total4) return;
    float4 v = *(const float4*)(x + idx * 4);
    ushort4 o;
    o.x = f2b(v.x); o.y = f2b(v.y); o.z = f2b(v.z); o.w = f2b(v.w);
    *(ushort4*)(out + idx * 4) = o;
}

// ---------------- all weights -> bf16 transposed, one dispatch -------------
__global__ void wconv_all(const float* __restrict__ W1, const float* __restrict__ W2,
                          const float* __restrict__ W3, const float* __restrict__ W4,
                          const float* __restrict__ W5, const float* __restrict__ W6,
                          ushort* __restrict__ B1, ushort* __restrict__ B2,
                          ushort* __restrict__ B3, ushort* __restrict__ B4,
                          ushort* __restrict__ B5, ushort* __restrict__ B6) {
    int idx = blockIdx.x * blockDim.x + threadIdx.x;
    if (idx < 6144) {                       // L1: 48*128
        int row = idx >> 7, k = idx & 127;
        int j = row >> 4, n = row & 15;
        B1[idx] = f2b(W1[(j * 128 + k) * 16 + n]);
    } else if (idx < 8192) {                // L2: 32*64, K=48
        int t = idx - 6144; int n = t >> 6, k = t & 63;
        B2[t] = f2b(k < 48 ? W2[k * 32 + n] : 0.f);
    } else if (idx < 14336) {               // L3: 64*96
        int t = idx - 8192; int n = t / 96, k = t - n * 96;
        B3[t] = f2b(W3[k * 64 + n]);
    } else if (idx < 38912) {               // L4: 128*192
        int t = idx - 14336; int n = t / 192, k = t - n * 192;
        B4[t] = f2b(W4[k * 128 + n]);
    } else if (idx < 137216) {              // L5: 256*384
        int t = idx - 38912; int n = t / 384, k = t - n * 384;
        B5[t] = f2b(W5[k * 256 + n]);
    } else if (idx < 530432) {              // L6: 512*768
        int t = idx - 137216; int n = t / 768, k = t - n * 768;
        B6[t] = f2b(W6[k * 512 + n]);
    }
}

// ---------------- SpMV gather, small FI (16/32): node-packed waves ---------
template <int FI>
__global__ __launch_bounds__(256) void lmv_bf16(
        const ushort* __restrict__ A, ushort* __restrict__ Out,
        const ushort* __restrict__ Sub, int ldi, int ldo,
        const int* __restrict__ offs, const int* __restrict__ rows,
        const float* __restrict__ w, float scale, int N) {
    constexpr int NPW = 64 / FI;
    int wave = threadIdx.x >> 6;
    int lane = threadIdx.x & 63;
    int sub = lane / FI;
    int fbase = lane & (FI - 1);
    int node = blockIdx.x * (4 * NPW) + wave * NPW + sub;
    if (node >= N) return;
    int e0 = offs[node], e1 = offs[node + 1];
    float acc[4];
    #pragma unroll
    for (int c = 0; c < 4; ++c) acc[c] = 0.f;
    int e = e0;
    for (; e + 4 <= e1; e += 4) {
        int r0 = rows[e], r1 = rows[e + 1], r2 = rows[e + 2], r3 = rows[e + 3];
        float w0 = w[e], w1 = w[e + 1], w2 = w[e + 2], w3 = w[e + 3];
        acc[0] += w0 * b2f(A[(size_t)r0 * ldi + fbase]);
        acc[1] += w1 * b2f(A[(size_t)r1 * ldi + fbase]);
        acc[2] += w2 * b2f(A[(size_t)r2 * ldi + fbase]);
        acc[3] += w3 * b2f(A[(size_t)r3 * ldi + fbase]);
    }
    for (; e < e1; ++e)
        acc[0] += w[e] * b2f(A[(size_t)rows[e] * ldi + fbase]);
    float a = (acc[0] + acc[1]) + (acc[2] + acc[3]);
    ushort* o = Out + (size_t)node * ldo + fbase;
    if (Sub) {
        const ushort* s = Sub + (size_t)node * ldo + fbase;
        *o = f2b(scale * a - b2f(*s));
    } else {
        *o = f2b(scale * a);
    }
}

// ---- L1 tail fused: z3 = Lhat@Z2 (16-wide), h1 = softplus(Y0+Z1+2z3-Y2+b) --
__global__ __launch_bounds__(256) void lmv_l1_final(
        const ushort* __restrict__ Z,    // (N,32) = [Z1|Z2]
        const ushort* __restrict__ Y,    // (N,48) = [Y0|Y1|Y2]
        const float* __restrict__ b,     // b1[16]
        ushort* __restrict__ Out,        // (N,64), cols [0,16)
        const int* __restrict__ offs, const int* __restrict__ rows,
        const float* __restrict__ w, int N) {
    int wave = threadIdx.x >> 6;
    int lane = threadIdx.x & 63;
    int sub = lane >> 4, f = lane & 15;
    int node = blockIdx.x * 16 + wave * 4 + sub;
    if (node >= N) return;
    int e0 = offs[node], e1 = offs[node + 1];
    const ushort* Z2 = Z + 16;
    float acc[4];
    #pragma unroll
    for (int c = 0; c < 4; ++c) acc[c] = 0.f;
    int e = e0;
    for (; e + 4 <= e1; e += 4) {
        int r0 = rows[e], r1 = rows[e + 1], r2 = rows[e + 2], r3 = rows[e + 3];
        float w0 = w[e], w1 = w[e + 1], w2 = w[e + 2], w3 = w[e + 3];
        acc[0] += w0 * b2f(Z2[(size_t)r0 * 32 + f]);
        acc[1] += w1 * b2f(Z2[(size_t)r1 * 32 + f]);
        acc[2] += w2 * b2f(Z2[(size_t)r2 * 32 + f]);
        acc[3] += w3 * b2f(Z2[(size_t)r3 * 32 + f]);
    }
    for (; e < e1; ++e)
        acc[0] += w[e] * b2f(Z2[(size_t)rows[e] * 32 + f]);
    float z3 = (acc[0] + acc[1]) + (acc[2] + acc[3]);
    float y0 = b2f(Y[(size_t)node * 48 + f]);
    float y2 = b2f(Y[(size_t)node * 48 + 32 + f]);
    float z1 = b2f(Z[(size_t)node * 32 + f]);
    float v = y0 + z1 + 2.f * z3 - y2 + b[f];
    Out[(size_t)node * 64 + f] = f2b(softplus_f(v));
}

// ---------------- SpMV gather, vectorized (FI = VEC*64), scalar CSR --------
// One wave per node; lane reads VEC contiguous bf16 -> one VMEM per edge.
// CSR via readfirstlane -> SGPR loop; CH=8 accumulator chains (CH=16 spilled
// acc[] to scratch -> 946 MB writes, 2x regression — R12 lesson).
template <int VEC>
__global__ __launch_bounds__(256) void lmv_vec(
        const ushort* __restrict__ A, ushort* __restrict__ Out,
        const ushort* __restrict__ Sub, int ld,
        const int* __restrict__ offs, const int* __restrict__ rows,
        const float* __restrict__ w, float scale) {
    constexpr int CH = 8;
    int node = blockIdx.x * 4 + (threadIdx.x >> 6);   // NN % 4 == 0, no guard
    int lane = threadIdx.x & 63;
    int fbase = lane * VEC;
    int e0 = __builtin_amdgcn_readfirstlane(offs[node]);
    int e1 = __builtin_amdgcn_readfirstlane(offs[node + 1]);
    float acc[CH][VEC];
    #pragma unroll
    for (int c = 0; c < CH; ++c)
        #pragma unroll
        for (int v = 0; v < VEC; ++v) acc[c][v] = 0.f;
    int e = e0;
    for (; e + CH <= e1; e += CH) {
        #pragma unroll
        for (int c = 0; c < CH; ++c) {
            int r = rows[e + c];            // scalar (uniform) load
            float we = w[e + c];
            const ushort* pr = A + (size_t)r * ld + fbase;
            if constexpr (VEC == 4) {
                ushort4 u = *(const ushort4*)pr;
                acc[c][0] += we * b2f(u.x); acc[c][1] += we * b2f(u.y);
                acc[c][2] += we * b2f(u.z); acc[c][3] += we * b2f(u.w);
            } else if constexpr (VEC == 2) {
                ushort2 u = *(const ushort2*)pr;
                acc[c][0] += we * b2f(u.x); acc[c][1] += we * b2f(u.y);
            } else {
                acc[c][0] += we * b2f(*pr);
            }
        }
    }
    for (; e < e1; ++e) {
        int c = e & (CH - 1);
        int r = rows[e];
        float we = w[e];
        const ushort* pr = A + (size_t)r * ld + fbase;
        if constexpr (VEC == 4) {
            ushort4 u = *(const ushort4*)pr;
            acc[c][0] += we * b2f(u.x); acc[c][1] += we * b2f(u.y);
            acc[c][2] += we * b2f(u.z); acc[c][3] += we * b2f(u.w);
        } else if constexpr (VEC == 2) {
            ushort2 u = *(const ushort2*)pr;
            acc[c][0] += we * b2f(u.x); acc[c][1] += we * b2f(u.y);
        } else {
            acc[c][0] += we * b2f(*pr);
        }
    }
    #pragma unroll
    for (int c = 1; c < CH; ++c)
        #pragma unroll
        for (int v = 0; v < VEC; ++v) acc[0][v] += acc[c][v];
    ushort* o = Out + (size_t)node * ld + fbase;
    if (Sub) {
        const ushort* s = Sub + (size_t)node * ld + fbase;
        ushort tmp[VEC];
        #pragma unroll
        for (int v = 0; v < VEC; ++v) tmp[v] = f2b(scale * acc[0][v] - b2f(s[v]));
        #pragma unroll
        for (int v = 0; v < VEC; ++v) o[v] = tmp[v];
    } else {
        #pragma unroll
        for (int v = 0; v < VEC; ++v) o[v] = f2b(scale * acc[0][v]);
    }
}

// ---------------- MFMA GEMM, BN<=64 path, BK=32, double-buffered LDS -------
// Pipeline: raw s_barrier + fine s_waitcnt vmcnt(N) keeps next tile's
// global_load_lds in flight across the barrier. Correctness validated R12.
template <int BN, bool ACT = true>
__global__ __launch_bounds__(256) void gemm_mfma(
        const ushort* __restrict__ A, int lda, int K,
        const ushort* __restrict__ Bt,
        const float* __restrict__ bias,
        ushort* __restrict__ Out, int ldo) {
    constexpr int BM = 128, BK = 32;
    constexpr int SM = 32;                    // 4 waves along M
    constexpr int FM = 2;
    constexpr int FN = BN / 16;
    constexpr int CB = BN / 16;               // B staging calls (1KB each)
    constexpr int WAITN = (BN == 64) ? 3 : 2; // per-wave loads/stage (min)
    __shared__ __align__(16) ushort As[2][BM][BK];
    __shared__ __align__(16) ushort Bs[2][BN][BK];
    int tid = threadIdx.x;
    int wv = tid >> 6, ln = tid & 63;
    int q = ln >> 4, r16 = ln & 15;
    int m0 = blockIdx.x * BM;

    int lrow = ln >> 2;
    int gseg = (ln & 3) ^ ((ln >> 3) & 3);
    const ushort* Abase = A + (size_t)(m0 + lrow) * lda + gseg * 8;
    const ushort* Bbase = Bt + (size_t)lrow * K + gseg * 8;

    floatx4 acc[FM][FN];
    #pragma unroll
    for (int i = 0; i < FM; ++i)
        #pragma unroll
        for (int j = 0; j < FN; ++j) acc[i][j] = (floatx4){0.f, 0.f, 0.f, 0.f};

    int sw = (q ^ ((r16 >> 1) & 3)) * 8;
    int aoff[FM], boff[FN];
    #pragma unroll
    for (int i = 0; i < FM; ++i) aoff[i] = (wv * SM + i * 16 + r16) * BK + sw;
    #pragma unroll
    for (int j = 0; j < FN; ++j) boff[j] = (j * 16 + r16) * BK + sw;

    auto stage = [&](int b, int k0) {
        gld_lds16(Abase + (size_t)(wv * 16) * lda + k0, &As[b][wv * 16][0]);
        gld_lds16(Abase + (size_t)(64 + wv * 16) * lda + k0, &As[b][64 + wv * 16][0]);
        if constexpr (CB == 4) {
            gld_lds16(Bbase + (size_t)(wv * 16) * K + k0, &Bs[b][wv * 16][0]);
        } else {
            if (wv < CB) gld_lds16(Bbase + (size_t)(wv * 16) * K + k0, &Bs[b][wv * 16][0]);
        }
    };
    auto compute = [&](int b) {
        const ushort* ldsA = &As[b][0][0];
        const ushort* ldsB = &Bs[b][0][0];
        short8 af[FM], bf[FN];
        #pragma unroll
        for (int i = 0; i < FM; ++i) af[i] = *(const short8*)(ldsA + aoff[i]);
        #pragma unroll
        for (int j = 0; j < FN; ++j) bf[j] = *(const short8*)(ldsB + boff[j]);
        #pragma unroll
        for (int i = 0; i < FM; ++i)
            #pragma unroll
            for (int j = 0; j < FN; ++j)
                acc[i][j] = __builtin_amdgcn_mfma_f32_16x16x32_bf16(
                    af[i], bf[j], acc[i][j], 0, 0, 0);
    };

    int nIter = K / BK;
    stage(0, 0);
    for (int i = 0; i < nIter; ++i) {
        int cur = i & 1;
        barrier_raw();                    // all waves done reading buf cur^1
        if (i + 1 < nIter) {
            stage(cur ^ 1, (i + 1) * BK); // prefetch next tile
            waitcnt_vm<WAITN>();          // own tile-i loads landed
        } else {
            waitcnt_vm<0>();
        }
        barrier_raw();                    // tile i complete in LDS
        compute(cur);
    }
    #pragma unroll
    for (int i = 0; i < FM; ++i) {
        #pragma unroll
        for (int j = 0; j < FN; ++j) {
            int n = j * 16 + r16;
            float bv = ACT ? bias[n] : 0.f;
            #pragma unroll
            for (int r = 0; r < 4; ++r) {
                int m = m0 + wv * SM + i * 16 + q * 4 + r;
                float v = acc[i][j][r] + bv;
                Out[(size_t)m * ldo + n] = f2b(ACT ? softplus_f(v) : v);
            }
        }
    }
}

// ---------------- MFMA GEMM, BN=128 path, BK=64 + double-buffered LDS ------
// 8 gld_lds16 per wave per stage; vmcnt(8) keeps next tile in flight across
// the barrier. FC: fused h@fcw -> per-(yb,wn) partial slot (8 total; wn waves
// see different column halves and must not share a destination).
template <bool FC = false, int YB = 0>
__global__ __launch_bounds__(256) void gemm_bk64(
        const ushort* __restrict__ A, int lda, int K,
        const ushort* __restrict__ Bt,
        const float* __restrict__ bias,
        ushort* __restrict__ Out, int ldo,
        const float* __restrict__ fcw, float* __restrict__ fcout) {
    constexpr int BM = 128, BN = 128, BK = 64;
    __shared__ __align__(16) ushort As[2][BM][BK];   // 2 x 16 KB
    __shared__ __align__(16) ushort Bs[2][BN][BK];   // 2 x 16 KB
    int tid = threadIdx.x;
    int wv = tid >> 6, ln = tid & 63;
    int wm = wv & 1, wn = wv >> 1;
    int q = ln >> 4, r16 = ln & 15;
    int yb = blockIdx.x & ((1 << YB) - 1);
    int xb = blockIdx.x >> YB;
    int m0 = xb * BM;
    int n0 = yb * BN;

    int lrow8 = ln >> 3, slds = ln & 7;
    int gseg = slds ^ lrow8;
    const ushort* Abase = A + (size_t)(m0 + lrow8) * lda + gseg * 8;
    const ushort* Bbase = Bt + (size_t)(n0 + lrow8) * K + gseg * 8;

    floatx4 acc[4][4];
    #pragma unroll
    for (int i = 0; i < 4; ++i)
        #pragma unroll
        for (int j = 0; j < 4; ++j) acc[i][j] = (floatx4){0.f, 0.f, 0.f, 0.f};

    int r7 = r16 & 7;
    int aoff[2][4], boff[2][4];
    #pragma unroll
    for (int s = 0; s < 2; ++s) {
        int segp = ((s * 4 + q) ^ r7) * 8;
        #pragma unroll
        for (int i = 0; i < 4; ++i) {
            aoff[s][i] = (wm * 64 + i * 16 + r16) * BK + segp;
            boff[s][i] = (wn * 64 + i * 16 + r16) * BK + segp;
        }
    }

    auto stage = [&](int b, int k0) {
        #pragma unroll
        for (int g = 0; g < 4; ++g)
            gld_lds16(Abase + (size_t)(wv * 8 + g * 32) * lda + k0,
                      &As[b][wv * 8 + g * 32][0]);
        #pragma unroll
        for (int g = 0; g < 4; ++g)
            gld_lds16(Bbase + (size_t)(wv * 8 + g * 32) * K + k0,
                      &Bs[b][wv * 8 + g * 32][0]);
    };
    auto compute = [&](int b) {
        const ushort* ldsA = &As[b][0][0];
        const ushort* ldsB = &Bs[b][0][0];
        #pragma unroll
        for (int s = 0; s < 2; ++s) {
            short8 af[4], bf[4];
            #pragma unroll
            for (int i = 0; i < 4; ++i) af[i] = *(const short8*)(ldsA + aoff[s][i]);
            #pragma unroll
            for (int j = 0; j < 4; ++j) bf[j] = *(const short8*)(ldsB + boff[s][j]);
            #pragma unroll
            for (int i = 0; i < 4; ++i)
                #pragma unroll
                for (int j = 0; j < 4; ++j)
                    acc[i][j] = __builtin_amdgcn_mfma_f32_16x16x32_bf16(
                        af[i], bf[j], acc[i][j], 0, 0, 0);
        }
    };

    int nIter = K / BK;
    stage(0, 0);
    for (int i = 0; i < nIter; ++i) {
        int cur = i & 1;
        barrier_raw();                    // all waves done reading buf cur^1
        if (i + 1 < nIter) {
            stage(cur ^ 1, (i + 1) * BK);
            waitcnt_vm<8>();              // own tile-i loads landed
        } else {
            waitcnt_vm<0>();
        }
        barrier_raw();                    // tile i complete in LDS
        compute(cur);
    }

    if constexpr (FC) {
        int pb = yb * 2 + wn;   // per-(yb,wn) partial slot — no shared dst
        #pragma unroll
        for (int i = 0; i < 4; ++i) {
            #pragma unroll
            for (int r = 0; r < 4; ++r) {
                float p0 = 0.f, p1 = 0.f, p2 = 0.f;
                #pragma unroll
                for (int j = 0; j < 4; ++j) {
                    int n = n0 + wn * 64 + j * 16 + r16;
                    float v = softplus_f(acc[i][j][r] + bias[n]);
                    p0 += v * fcw[n * 3 + 0];
                    p1 += v * fcw[n * 3 + 1];
                    p2 += v * fcw[n * 3 + 2];
                }
                #pragma unroll
                for (int off = 1; off < 16; off <<= 1) {
                    p0 += __shfl_xor(p0, off);
                    p1 += __shfl_xor(p1, off);
                    p2 += __shfl_xor(p2, off);
                }
                if (r16 == 0) {
                    int m = m0 + wm * 64 + i * 16 + q * 4 + r;
                    float* dst = fcout + ((size_t)pb * MPAD + m) * 3;
                    dst[0] = p0; dst[1] = p1; dst[2] = p2;
                }
            }
        }
    } else {
        #pragma unroll
        for (int i = 0; i < 4; ++i) {
            #pragma unroll
            for (int j = 0; j < 4; ++j) {
                int n = n0 + wn * 64 + j * 16 + r16;
                float bv = bias[n];
                #pragma unroll
                for (int r = 0; r < 4; ++r) {
                    int m = m0 + wm * 64 + i * 16 + q * 4 + r;
                    Out[(size_t)m * ldo + n] = f2b(softplus_f(acc[i][j][r] + bv));
                }
            }
        }
    }
}

// ---------------- FC partial reduce: out = sum of 8 partials + fcb ---------
__global__ __launch_bounds__(256) void fc_reduce(
        const float* __restrict__ part, const float* __restrict__ fcb,
        float* __restrict__ out) {
    int idx = blockIdx.x * blockDim.x + threadIdx.x;
    if (idx >= NN * 3) return;
    int c = idx - (idx / 3) * 3;
    float s = 0.f;
    #pragma unroll
    for (int pb = 0; pb < 8; ++pb)
        s += part[(size_t)pb * MPAD * 3 + idx];
    out[idx] = s + fcb[c];
}

static inline size_t align256(size_t x) { return (x + 255) & ~(size_t)255; }

extern "C" void kernel_launch(void* const* d_in, const int* in_sizes, int n_in,
                              void* d_out, int out_size, void* d_ws, size_t ws_size,
                              hipStream_t stream) {
    const float* x   = (const float*)d_in[0];
    const int*   ei  = (const int*)d_in[1];
    const float* ew  = (const float*)d_in[2];
    const float* W[6]  = { (const float*)d_in[4],  (const float*)d_in[6],
                           (const float*)d_in[8],  (const float*)d_in[10],
                           (const float*)d_in[12], (const float*)d_in[14] };
    const float* Bv[6] = { (const float*)d_in[5],  (const float*)d_in[7],
                           (const float*)d_in[9],  (const float*)d_in[11],
                           (const float*)d_in[13], (const float*)d_in[15] };
    const float* fc_w = (const float*)d_in[16];
    const float* fc_b = (const float*)d_in[17];
    float* out = (float*)d_out;

    const int* e_row = ei;        // edge_index[0]
    const int* e_col = ei + EE;   // edge_index[1]

    // layers 2..6 (index 1..5)
    const int fi_arr[5]   = { 16, 32, 64, 128, 256 };
    const int fo_arr[5]   = { 32, 64, 128, 256, 512 };
    const int Kpad_arr[5] = { 64, 96, 192, 384, 768 };
    const int ldo_arr[5]  = { 96, 192, 384, 768, 512 };

    // ---- workspace carve ----
    char* p = (char*)d_ws;
    float* deg    = (float*)p; p += align256((size_t)NN * 4);
    int*   counts = (int*)p;   p += align256((size_t)NN * 4);
    int*   offs   = (int*)p;   p += align256((size_t)(NN + 1) * 4);
    int*   cursor = (int*)p;   p += align256((size_t)NN * 4);
    int*   bsums  = (int*)p;   p += align256((size_t)SCAN_B * 4);
    int*   csr_r  = (int*)p;   p += align256((size_t)EE * 4);
    float* csr_w  = (float*)p; p += align256((size_t)EE * 4);
    ushort* Bt1   = (ushort*)p; p += align256((size_t)48 * 128 * 2);
    ushort* Bt[5];
    for (int L = 0; L < 5; ++L) {
        Bt[L] = (ushort*)p;
        p += align256((size_t)fo_arr[L] * Kpad_arr[L] * 2);
    }
    float* fcpart = (float*)p; p += align256((size_t)8 * MPAD * 3 * 4);
    ushort* xb   = (ushort*)p; p += align256((size_t)MPAD * 128 * 2);
    ushort* Ybuf = (ushort*)p; p += align256((size_t)MPAD * 48 * 2);
    ushort* Zbuf = (ushort*)p; p += align256((size_t)MPAD * 32 * 2);
    ushort* buf0 = (ushort*)p; p += align256((size_t)MPAD * 768 * 2);
    ushort* buf1 = (ushort*)p; p += align256((size_t)MPAD * 768 * 2);
    (void)ws_size; (void)n_in; (void)in_sizes; (void)out_size;

    // ---- zero init: deg+counts only (adjacent -> one memset). Activation
    // buffer poison is harmless (pad rows never feed real rows; K-pad cols
    // multiply zeroed Bt cols). fcpart fully written before fc_reduce.
    hipMemsetAsync(deg, 0, align256((size_t)NN * 4) + (size_t)NN * 4, stream);

    // ---- graph preprocessing ----
    {
        int blocks = (EE + 255) / 256;
        edge_pass1<<<blocks, 256, 0, stream>>>(e_row, e_col, ew, deg, counts, EE);
        scan_part<<<SCAN_B, 256, 0, stream>>>(counts, bsums, NN);
        scan_tops<<<1, 64, 0, stream>>>(bsums);
        scan_final<<<SCAN_B, 256, 0, stream>>>(counts, bsums, offs, cursor, NN);
        edge_pass2<<<blocks, 256, 0, stream>>>(e_row, e_col, ew, deg, cursor, csr_r, csr_w, EE);
    }

    // ---- all weights -> bf16 transposed, one dispatch ----
    wconv_all<<<(530432 + 255) / 256, 256, 0, stream>>>(
        W[0], W[1], W[2], W[3], W[4], W[5],
        Bt1, Bt[0], Bt[1], Bt[2], Bt[3], Bt[4]);

    // ---- x -> bf16 dense (N,128) ----
    copy_x_kernel<<<(NN * 128 / 4 + 255) / 256, 256, 0, stream>>>(x, xb, NN * 128 / 4);

    // ---- Layer 1 in output space: Y = x @ [W0|W1|W2]  (30080 x 48, K=128) --
    gemm_mfma<48, false><<<dim3(MPAD / 128), 256, 0, stream>>>(
        xb, 128, 128, Bt1, nullptr, Ybuf, 48);
    // Z = Lhat @ [Y1|Y2]  (32-wide)
    lmv_bf16<32><<<(NN + 7) / 8, 256, 0, stream>>>(
        Ybuf + 16, Zbuf, nullptr, 48, 32, offs, csr_r, csr_w, 1.0f, NN);
    // fused: z3 = Lhat@Z2 ; h1 = softplus(Y0+Z1+2z3-Y2+b1) -> buf1 [0,16), ld 64
    lmv_l1_final<<<(NN + 15) / 16, 256, 0, stream>>>(
        Zbuf, Ybuf, Bv[0], buf1, offs, csr_r, csr_w, NN);

    // ---- Layers 2..6 ----
    ushort* Abuf[5] = { buf1, buf0, buf1, buf0, buf1 };
    ushort* Obuf[5] = { buf0, buf1, buf0, buf1, buf0 };

    for (int L = 0; L < 5; ++L) {
        int fi = fi_arr[L];
        int ldA = Kpad_arr[L];
        int ldO = ldo_arr[L];
        ushort* A = Abuf[L];
        ushort* O = Obuf[L];

        // two SpMV passes: Tx1 = Lhat@Tx0; Tx2 = 2*Lhat@Tx1 - Tx0
        switch (fi) {
            case 16:
                lmv_bf16<16><<<(NN + 15) / 16, 256, 0, stream>>>(
                    A, A + fi, nullptr, ldA, ldA, offs, csr_r, csr_w, 1.0f, NN);
                lmv_bf16<16><<<(NN + 15) / 16, 256, 0, stream>>>(
                    A + fi, A + 2 * fi, A, ldA, ldA, offs, csr_r, csr_w, 2.0f, NN);
                break;
            case 32:
                lmv_bf16<32><<<(NN + 7) / 8, 256, 0, stream>>>(
                    A, A + fi, nullptr, ldA, ldA, offs, csr_r, csr_w, 1.0f, NN);
                lmv_bf16<32><<<(NN + 7) / 8, 256, 0, stream>>>(
                    A + fi, A + 2 * fi, A, ldA, ldA, offs, csr_r, csr_w, 2.0f, NN);
                break;
            case 64:
                lmv_vec<1><<<NN / 4, 256, 0, stream>>>(
                    A, A + fi, nullptr, ldA, offs, csr_r, csr_w, 1.0f);
                lmv_vec<1><<<NN / 4, 256, 0, stream>>>(
                    A + fi, A + 2 * fi, A, ldA, offs, csr_r, csr_w, 2.0f);
                break;
            case 128:
                lmv_vec<2><<<NN / 4, 256, 0, stream>>>(
                    A, A + fi, nullptr, ldA, offs, csr_r, csr_w, 1.0f);
                lmv_vec<2><<<NN / 4, 256, 0, stream>>>(
                    A + fi, A + 2 * fi, A, ldA, offs, csr_r, csr_w, 2.0f);
                break;
            default:  // 256
                lmv_vec<4><<<NN / 4, 256, 0, stream>>>(
                    A, A + fi, nullptr, ldA, offs, csr_r, csr_w, 1.0f);
                lmv_vec<4><<<NN / 4, 256, 0, stream>>>(
                    A + fi, A + 2 * fi, A, ldA, offs, csr_r, csr_w, 2.0f);
                break;
        }

        int K = Kpad_arr[L];
        switch (fo_arr[L]) {
            case 32:
                gemm_mfma<32><<<dim3(MPAD / 128), 256, 0, stream>>>(
                    A, ldA, K, Bt[L], Bv[L + 1], O, ldO);
                break;
            case 64:
                gemm_mfma<64><<<dim3(MPAD / 128), 256, 0, stream>>>(
                    A, ldA, K, Bt[L], Bv[L + 1], O, ldO);
                break;
            case 128:   // K=192, BK=64 DB
                gemm_bk64<false, 0><<<dim3(MPAD / 128), 256, 0, stream>>>(
                    A, ldA, K, Bt[L], Bv[L + 1], O, ldO, nullptr, nullptr);
                break;
            case 256:   // K=384, y-inner (id&1)
                gemm_bk64<false, 1><<<dim3(MPAD / 128 * 2), 256, 0, stream>>>(
                    A, ldA, K, Bt[L], Bv[L + 1], O, ldO, nullptr, nullptr);
                break;
            default:    // 512 = layer 6: K=768, fused FC -> 8 partial buffers
                gemm_bk64<true, 2><<<dim3(MPAD / 128 * 4), 256, 0, stream>>>(
                    A, ldA, K, Bt[L], Bv[L + 1], nullptr, 0, fc_w, fcpart);
                break;
        }
    }

    // ---- final: out = sum of 8 FC partials + fc_b ----
    fc_reduce<<<(NN * 3 + 255) / 256, 256, 0, stream>>>(fcpart, fc_b, out);
}